// Round 7
// baseline (182.341 us; speedup 1.0000x reference)
//
#include <hip/hip_runtime.h>

// 8-bit ripple-borrow subtractor on 0/1-valued float32 rows. Index 7 = LSB.
// Output = [diffs (N,8) ; borrow (N,1)] flat.
//
// R7: full grid (R6's win) + TWO adjacent rows per thread -> 8 outstanding
// 16B loads (MLP; R1-vs-R5 showed 4 loads > 2 loads), bitwise logic on the
// 0x3F800000 words (R6), and zero cross-lane ops: borrow-in is known per
// row so each row is a straight 8-step ripple; the two rows' chains run
// in parallel (ILP-2). Bin read as one dwordx2, Bout written as one dwordx2.
// NOT R4's mistake: rows are adjacent (no second distant stream, no cap).

typedef unsigned int u32;
typedef u32 u32x4 __attribute__((ext_vector_type(4)));
typedef u32 u32x2 __attribute__((ext_vector_type(2)));
#define FONE 0x3F800000u  // bit pattern of 1.0f

// 8-bit ripple, bitwise on {0, FONE} words. hi = bits 0-3 (MSB half),
// lo = bits 4-7 (LSB half). Returns diff halves + final borrow word.
__device__ __forceinline__ void ripple8(const u32x4 hi, const u32x4 lo, 
                                        const u32x4 bhi, const u32x4 blo,
                                        u32 bin, u32x4& dhi, u32x4& dlo, u32& bout)
{
    u32 av[8] = {hi.x, hi.y, hi.z, hi.w, lo.x, lo.y, lo.z, lo.w};
    u32 bv[8] = {bhi.x, bhi.y, bhi.z, bhi.w, blo.x, blo.y, blo.z, blo.w};
    u32 dv[8];
    u32 bor = bin;
    #pragma unroll
    for (int j = 7; j >= 0; --j) {   // index 7 = LSB
        u32 x  = av[j] ^ bv[j];
        u32 na = av[j] ^ FONE;
        u32 g  = na & bv[j];
        u32 p  = na | bv[j];         // (na&c)|(b&c) == (na|b)&c
        dv[j]  = x ^ bor;
        bor    = g | (p & bor);
    }
    dhi = (u32x4){dv[0], dv[1], dv[2], dv[3]};
    dlo = (u32x4){dv[4], dv[5], dv[6], dv[7]};
    bout = bor;
}

__global__ __launch_bounds__(256) void sub8_kernel(
    const u32x4* __restrict__ A4, const u32x4* __restrict__ B4,
    const u32x2* __restrict__ Bin2, u32x4* __restrict__ D4,
    u32x2* __restrict__ Bout2, int nt /* = N/2 threads */)
{
    int t = blockIdx.x * blockDim.x + threadIdx.x;
    if (t >= nt) return;

    // Rows 2t and 2t+1. Issue all 8 vector loads + 1 dwordx2 up front.
    u32x4 a0 = A4[4 * t],     a1 = A4[4 * t + 1];
    u32x4 a2 = A4[4 * t + 2], a3 = A4[4 * t + 3];
    u32x4 b0 = B4[4 * t],     b1 = B4[4 * t + 1];
    u32x4 b2 = B4[4 * t + 2], b3 = B4[4 * t + 3];
    u32x2 bin = Bin2[t];

    u32x4 d0, d1, d2, d3;
    u32 bo0, bo1;
    ripple8(a0, a1, b0, b1, bin.x, d0, d1, bo0);   // row 2t
    ripple8(a2, a3, b2, b3, bin.y, d2, d3, bo1);   // row 2t+1

    D4[4 * t]     = d0;
    D4[4 * t + 1] = d1;
    D4[4 * t + 2] = d2;
    D4[4 * t + 3] = d3;
    Bout2[t] = (u32x2){bo0, bo1};
}

extern "C" void kernel_launch(void* const* d_in, const int* in_sizes, int n_in,
                              void* d_out, int out_size, void* d_ws, size_t ws_size,
                              hipStream_t stream) {
    const u32* A   = (const u32*)d_in[0];
    const u32* B   = (const u32*)d_in[1];
    const u32* Bin = (const u32*)d_in[2];
    int n  = in_sizes[0] / 8;             // rows
    int nt = n / 2;                       // two rows per thread

    u32* D    = (u32*)d_out;              // (N,8) diffs
    u32* Bout = D + (size_t)n * 8;        // (N,1) borrow-out

    const int block = 256;
    int grid = (nt + block - 1) / block;  // full grid, no cap (16384 blocks)

    sub8_kernel<<<grid, block, 0, stream>>>(
        (const u32x4*)A, (const u32x4*)B, (const u32x2*)Bin,
        (u32x4*)D, (u32x2*)Bout, nt);
}

// Round 8
// 158.909 us; speedup vs baseline: 1.1475x; 1.1475x over previous
//
#include <hip/hip_runtime.h>

// 8-bit ripple-borrow subtractor on 0/1-valued float32 rows. Index 7 = LSB.
// Output = [diffs (N,8) ; borrow (N,1)] flat.
//
// R8 = R6 (contiguous half-row-per-thread carry-select, bitwise on the
// 0x3F800000 words, full grid) + doubled MLP: each thread handles TWO
// half-rows at base+tid and base+tid+256 within its block's contiguous
// 512-half-row chunk. Every load/store instruction stays perfectly
// lane-contiguous (R7's 64B-lane-stride indexing quadrupled TA requests
// and regressed). Both rows' borrow bits pack into one shfl_xor(1).

typedef unsigned int u32;
typedef u32 u32x4 __attribute__((ext_vector_type(4)));
#define FONE 0x3F800000u  // bit pattern of 1.0f

// Dual-hypothesis 4-bit ripple (carry-select) on {0,FONE} words.
// Local index 3 = less-significant end of the half.
__device__ __forceinline__ void half_ripple2(const u32x4 a, const u32x4 b,
                                             u32x4& d0, u32x4& d1,
                                             u32& bo0, u32& bo1)
{
    u32 av[4] = {a.x, a.y, a.z, a.w};
    u32 bv[4] = {b.x, b.y, b.z, b.w};
    u32 d0v[4], d1v[4];
    u32 bor0 = 0u, bor1 = FONE;
    #pragma unroll
    for (int j = 3; j >= 0; --j) {
        u32 na = av[j] ^ FONE;
        u32 x  = av[j] ^ bv[j];
        u32 g  = na & bv[j];
        u32 p  = na | bv[j];      // (na&c)|(b&c) == (na|b)&c
        d0v[j] = x ^ bor0;
        d1v[j] = x ^ bor1;
        bor0 = g | (p & bor0);
        bor1 = g | (p & bor1);
    }
    d0 = (u32x4){d0v[0], d0v[1], d0v[2], d0v[3]};
    d1 = (u32x4){d1v[0], d1v[1], d1v[2], d1v[3]};
    bo0 = bor0; bo1 = bor1;
}

__global__ __launch_bounds__(256) void sub8_kernel(
    const u32x4* __restrict__ A4, const u32x4* __restrict__ B4,
    const u32* __restrict__ Bin, u32x4* __restrict__ D4,
    u32* __restrict__ Bout, int n2 /* = 2*N half-rows */)
{
    const int tid  = threadIdx.x;
    const int h1   = blockIdx.x * 512 + tid;   // first half-row
    const int h2   = h1 + 256;                 // second half-row
    const bool odd = (tid & 1) != 0;           // odd lane = LSB half (idx 4-7)

    if (h2 < n2) {
        // Issue all 4 contiguous vector loads + 2 scalar loads up front.
        u32x4 a1 = A4[h1], a2 = A4[h2];
        u32x4 b1 = B4[h1], b2 = B4[h2];
        const int r1 = h1 >> 1, r2 = h2 >> 1;
        u32 binw1 = Bin[r1], binw2 = Bin[r2];

        u32x4 p10, p11, p20, p21;
        u32 bo10, bo11, bo20, bo21;
        half_ripple2(a1, b1, p10, p11, bo10, bo11);
        half_ripple2(a2, b2, p20, p21, bo20, bo21);

        // Odd lanes resolve with Bin; pack both rows' borrow-outs in one shfl.
        u32 bl1 = binw1 ? bo11 : bo10;          // valid on odd lanes
        u32 bl2 = binw2 ? bo21 : bo20;
        u32 pk  = (bl1 ? 1u : 0u) | (bl2 ? 2u : 0u);
        u32 px  = __shfl_xor(pk, 1);

        u32 mb1 = odd ? binw1 : (px & 1u);      // nonzero = borrow
        u32 mb2 = odd ? binw2 : (px & 2u);

        D4[h1] = mb1 ? p11 : p10;               // contiguous 16 B/lane
        D4[h2] = mb2 ? p21 : p20;

        if (!odd) {                             // even lane = MSB half: final borrow
            Bout[r1] = mb1 ? bo11 : bo10;
            Bout[r2] = mb2 ? bo21 : bo20;
        }
    } else if (h1 < n2) {
        // Tail (pairs diverge together since n2 is even): single half-row.
        u32x4 a1 = A4[h1], b1 = B4[h1];
        const int r1 = h1 >> 1;
        u32 binw1 = Bin[r1];
        u32x4 p10, p11;
        u32 bo10, bo11;
        half_ripple2(a1, b1, p10, p11, bo10, bo11);
        u32 bl1 = binw1 ? bo11 : bo10;
        u32 px  = __shfl_xor(bl1, 1);
        u32 mb1 = odd ? binw1 : px;
        D4[h1] = mb1 ? p11 : p10;
        if (!odd) Bout[r1] = mb1 ? bo11 : bo10;
    }
}

extern "C" void kernel_launch(void* const* d_in, const int* in_sizes, int n_in,
                              void* d_out, int out_size, void* d_ws, size_t ws_size,
                              hipStream_t stream) {
    const u32* A   = (const u32*)d_in[0];
    const u32* B   = (const u32*)d_in[1];
    const u32* Bin = (const u32*)d_in[2];
    int n  = in_sizes[0] / 8;             // rows
    int n2 = n * 2;                       // half-rows

    u32* D    = (u32*)d_out;              // (N,8) diffs
    u32* Bout = D + (size_t)n * 8;        // (N,1) borrow-out

    const int block = 256;
    int grid = (n2 + 511) / 512;          // 512 half-rows per block (32768 blocks)

    sub8_kernel<<<grid, block, 0, stream>>>(
        (const u32x4*)A, (const u32x4*)B, Bin, (u32x4*)D, Bout, n2);
}

// Round 9
// 149.364 us; speedup vs baseline: 1.2208x; 1.0639x over previous
//
#include <hip/hip_runtime.h>

// 8-bit ripple-borrow subtractor on 0/1-valued float32 rows. Index 7 = LSB.
// Output = [diffs (N,8) ; borrow (N,1)] flat.
//
// R9 = R6 (best: 154 µs — contiguous half-row-per-thread carry-select,
// bitwise logic on 0x3F800000 words, full grid, one shfl_xor per row)
// + NONTEMPORAL stores. R3's NT write-amplification was caused by the
// 32B-lane-stride interleaved store pattern (partial sectors); R6's stores
// are perfectly lane-contiguous (full 64B sectors per instruction), so NT
// here only bypasses L2/L3 write allocation -> no fill/tag contention with
// the read re-scan stream. Key check: WRITE_SIZE must stay ~288 MiB.

typedef unsigned int u32;
typedef u32 u32x4 __attribute__((ext_vector_type(4)));
#define FONE 0x3F800000u  // bit pattern of 1.0f

__global__ __launch_bounds__(256) void sub8_kernel(
    const u32x4* __restrict__ A4, const u32x4* __restrict__ B4,
    const u32* __restrict__ Bin, u32x4* __restrict__ D4,
    u32* __restrict__ Bout, int n2 /* = 2*N half-rows */)
{
    int t = blockIdx.x * blockDim.x + threadIdx.x;
    if (t >= n2) return;
    const bool odd = (t & 1) != 0;  // odd lane = LSB half (indices 4-7)
    const int  r   = t >> 1;        // row

    u32x4 a = A4[t];                // contiguous 16 B/lane
    u32x4 b = B4[t];
    u32 binw = Bin[r];              // 0 or FONE (raw borrow-in word)

    // Dual 4-bit ripple (carry-select), bitwise on {0, FONE} words.
    u32 av[4] = {a.x, a.y, a.z, a.w};
    u32 bv[4] = {b.x, b.y, b.z, b.w};
    u32 d0v[4], d1v[4];
    u32 bor0 = 0u, bor1 = FONE;     // borrow-in = 0 / 1 hypotheses
    #pragma unroll
    for (int j = 3; j >= 0; --j) { // local index 3 = less-significant end
        u32 na = av[j] ^ FONE;
        u32 x  = av[j] ^ bv[j];
        u32 g  = na & bv[j];
        u32 p  = na | bv[j];       // (na&c)|(b&c) == (na|b)&c
        d0v[j] = x ^ bor0;
        d1v[j] = x ^ bor1;
        bor0 = g | (p & bor0);
        bor1 = g | (p & bor1);
    }

    // Odd lane resolves with Bin; ships its borrow-out to the even lane.
    u32 bout_low = binw ? bor1 : bor0;            // valid on odd lanes
    u32 xs = __shfl_xor(bout_low, 1);
    u32 myborrow = odd ? binw : xs;               // 0 or FONE

    u32x4 d = myborrow ? (u32x4){d1v[0], d1v[1], d1v[2], d1v[3]}
                       : (u32x4){d0v[0], d0v[1], d0v[2], d0v[3]};
    __builtin_nontemporal_store(d, &D4[t]);       // contiguous 16 B/lane

    if (!odd)                       // even lane holds the final (MSB) borrow
        __builtin_nontemporal_store(myborrow ? bor1 : bor0, &Bout[r]);
}

extern "C" void kernel_launch(void* const* d_in, const int* in_sizes, int n_in,
                              void* d_out, int out_size, void* d_ws, size_t ws_size,
                              hipStream_t stream) {
    const u32* A   = (const u32*)d_in[0];
    const u32* B   = (const u32*)d_in[1];
    const u32* Bin = (const u32*)d_in[2];
    int n  = in_sizes[0] / 8;             // rows
    int n2 = n * 2;                       // half-rows (one per thread)

    u32* D    = (u32*)d_out;              // (N,8) diffs
    u32* Bout = D + (size_t)n * 8;        // (N,1) borrow-out

    const int block = 256;
    int grid = (n2 + block - 1) / block;  // full grid, no cap (65536 blocks)

    sub8_kernel<<<grid, block, 0, stream>>>(
        (const u32x4*)A, (const u32x4*)B, Bin, (u32x4*)D, Bout, n2);
}